// Round 3
// baseline (483.592 us; speedup 1.0000x reference)
//
#include <hip/hip_runtime.h>

#define BB 16
#define RR 64
#define SS 128
#define MM 64
#define LL 128
#define EE 4032

// out layout (fp32, concatenated):
// inc_add [131072] | inc_gain [131072] | mean_s [4194304] | logstd_s | msg_s
#define OUT3_OFF 262144
#define ARR_SZ   4194304

// direct global->LDS, 16B per lane. LDS dest = wave-uniform base + lane*16.
__device__ __forceinline__ void g2l16(const float* g, const float* l) {
  __builtin_amdgcn_global_load_lds(
      (const __attribute__((address_space(1))) unsigned int*)g,
      (__attribute__((address_space(3))) unsigned int*)l, 16, 0, 0);
}

// ---------------------------------------------------------------------------
__global__ __launch_bounds__(256) void k_zero(float* __restrict__ out) {
  int tid = blockIdx.x * 256 + threadIdx.x;
  if (tid < 262144) { out[tid] = 0.0f; return; }
  int idx = tid - 262144;          // < 196608
  int a = idx >> 16;
  int r = idx & 65535;
  int b = r >> 12;
  int d = (r >> 6) & 63;
  int m = r & 63;
  out[OUT3_OFF + (size_t)a * ARR_SZ + (size_t)b * 262144 + d * 4160 + m] = 0.0f;
}

// ---------------------------------------------------------------------------
// k_edge v3: all staging via global_load_lds with counted vmcnt.
// LDS (floats): src [0,2048) stride-128 rows | meanW ring [2048,6144) |
// logstdW ring [6144,10240). Ring = 4 chunks x 1024 floats (chunk = 16
// floats of all 64 m-rows). Wave w stages AND consumes rows 16w..16w+15:
// weight traffic is lane-self-read -> no barriers, only per-wave vmcnt.
// Issue order per wave: [src x2][ch0..ch3 x2] -> vmcnt(8)+s_barrier ->
// per chunk: vmcnt(N) (N = #loads issued after that chunk), consume,
// reissue ch+4 into the just-freed slot (sched_barrier-pinned).
// ---------------------------------------------------------------------------
__global__ __launch_bounds__(256) void k_edge(
    const float* __restrict__ source,
    const float* __restrict__ mean_w,
    const float* __restrict__ mean_b,
    const float* __restrict__ logstd_w,
    const float* __restrict__ logstd_b,
    const int* __restrict__ src_idx,
    const int* __restrict__ tgt_idx,
    float* __restrict__ out)
{
  __shared__ float lds[10240];            // 40 KB -> ~4 blocks/CU
  const int e = blockIdx.x;
  const int tid = threadIdx.x;
  const int w = tid >> 6, lane = tid & 63;
  const int sidx = src_idx[e];
  const int tidx = tgt_idx[e];

  // --- source staging: 2 g2l per wave (first in this wave's vmcnt queue).
  // f enumerates 0..511 = b*32 + s4; LDS[f*4..f*4+3] = source[b][sidx][s4*4..]
  {
    int f0 = tid;
    g2l16(source + (size_t)(f0 >> 5) * (RR * SS) + (size_t)sidx * SS + (f0 & 31) * 4,
          lds + w * 256);
    int f1 = tid + 256;
    g2l16(source + (size_t)(f1 >> 5) * (RR * SS) + (size_t)sidx * SS + (f1 & 31) * 4,
          lds + 1024 + w * 256);
  }
  __builtin_amdgcn_sched_barrier(0);      // src loads stay oldest in queue

  // --- weight chunk issues: lane stages the exact 16B thread tid consumes
  const int row = w * 16 + (lane >> 2);   // == tid>>2 == m
  const int sq4 = (lane & 3) * 4;
  const float* wmg = mean_w   + (size_t)e * (MM * SS) + (size_t)row * SS + sq4;
  const float* wlg = logstd_w + (size_t)e * (MM * SS) + (size_t)row * SS + sq4;
  #pragma unroll
  for (int kk = 0; kk < 4; ++kk) {
    g2l16(wmg + kk * 16, lds + 2048 + kk * 1024 + w * 256);
    g2l16(wlg + kk * 16, lds + 6144 + kk * 1024 + w * 256);
  }
  __builtin_amdgcn_sched_barrier(0);

  asm volatile("s_waitcnt vmcnt(8)" ::: "memory");  // own src (oldest 2) landed
  __builtin_amdgcn_s_barrier();                     // all waves' src visible

  float accm[BB], accl[BB];
  #pragma unroll
  for (int b = 0; b < BB; ++b) { accm[b] = 0.0f; accl[b] = 0.0f; }

#define KSTEP(kk, Nwait)                                                        \
  {                                                                             \
    asm volatile("s_waitcnt vmcnt(" #Nwait ")" ::: "memory");                   \
    float4 a = *(const float4*)(lds + 2048 + ((kk) & 3) * 1024 + w * 256 + lane * 4); \
    float4 c = *(const float4*)(lds + 6144 + ((kk) & 3) * 1024 + w * 256 + lane * 4); \
    const int soff = sq4 + (kk) * 16;                                           \
    _Pragma("unroll")                                                           \
    for (int b = 0; b < BB; ++b) {                                              \
      float4 sv = *(const float4*)(lds + b * 128 + soff);                       \
      accm[b] = fmaf(a.x, sv.x, fmaf(a.y, sv.y, fmaf(a.z, sv.z, fmaf(a.w, sv.w, accm[b])))); \
      accl[b] = fmaf(c.x, sv.x, fmaf(c.y, sv.y, fmaf(c.z, sv.z, fmaf(c.w, sv.w, accl[b])))); \
    }                                                                           \
    if ((kk) < 4) {                                                             \
      __builtin_amdgcn_sched_barrier(0);  /* a,c consumed before slot reuse */  \
      g2l16(wmg + ((kk) + 4) * 16, lds + 2048 + (kk) * 1024 + w * 256);         \
      g2l16(wlg + ((kk) + 4) * 16, lds + 6144 + (kk) * 1024 + w * 256);         \
      __builtin_amdgcn_sched_barrier(0);                                        \
    }                                                                           \
  }

  // Nwait = #weight loads issued after chunk kk = min(6, 2*(7-kk))
  KSTEP(0, 6) KSTEP(1, 6) KSTEP(2, 6) KSTEP(3, 6)
  KSTEP(4, 6) KSTEP(5, 4) KSTEP(6, 2) KSTEP(7, 0)
#undef KSTEP

  // reduce the 4 s-quarters (adjacent lanes)
  #pragma unroll
  for (int b = 0; b < BB; ++b) {
    accm[b] += __shfl_xor(accm[b], 1);
    accm[b] += __shfl_xor(accm[b], 2);
    accl[b] += __shfl_xor(accl[b], 1);
    accl[b] += __shfl_xor(accl[b], 2);
  }
  const int m = tid >> 2;
  const int sq = tid & 3;
  const float bm = mean_b[e * MM + m];
  const float bl = logstd_b[e * MM + m];

  __syncthreads();                        // everyone done with lds; reuse for transpose
  #pragma unroll
  for (int j = 0; j < 4; ++j) {
    int b = sq * 4 + j;
    lds[b * 64 + m]        = accm[b] + bm;   // mean tile  [0,1024)
    lds[1024 + b * 64 + m] = accl[b] + bl;   // logstd tile [1024,2048)
  }
  __syncthreads();

  float* out3 = out + OUT3_OFF;
  float* out4 = out3 + ARR_SZ;
  float* out5 = out4 + ARR_SZ;
  const size_t rowbase = (size_t)(sidx * RR + tidx) * MM;
  const int b16 = tid >> 4, m4 = tid & 15;
  float4 vm = *(float4*)(lds + b16 * 64 + m4 * 4);
  float4 vl = *(float4*)(lds + 1024 + b16 * 64 + m4 * 4);
  size_t o = (size_t)b16 * (RR * RR * MM) + rowbase + m4 * 4;
  *(float4*)(out3 + o) = vm;
  *(float4*)(out4 + o) = vl;
  *(float4*)(out5 + o) = vm;
}

// ---------------------------------------------------------------------------
// k_inc: unchanged from v2 this round (isolate the g2l experiment to k_edge).
// ---------------------------------------------------------------------------
__global__ __launch_bounds__(256) void k_inc(
    const float* __restrict__ add_w,
    const float* __restrict__ gain_w,
    float* __restrict__ out)
{
  __shared__ float lds_mean[2][BB * 64];
  const int g = blockIdx.x;        // 64*2*9 = 1152
  const int tt = g / 18;
  const int r = g % 18;
  const int lh = r / 9;
  const int c = r % 9;
  const int tid = threadIdx.x;
  const int l_loc = tid >> 2;
  const int mq = tid & 3;
  const int l = lh * 64 + l_loc;
  const int b16 = tid >> 4, m4 = tid & 15;

  const float* out3 = out + OUT3_OFF;

  float acca[BB], accg[BB];
  #pragma unroll
  for (int b = 0; b < BB; ++b) { acca[b] = 0.0f; accg[b] = 0.0f; }

  float4 mv_n;
  float4 wa_n[4], wg_n[4];
  {
    const int si = c * 7;
    const int s = si + (si >= tt ? 1 : 0);
    const int e = s * 63 + (tt > s ? tt - 1 : tt);
    mv_n = *(const float4*)(out3 + ((size_t)b16 * 262144 + (size_t)(s * 64 + tt) * 64 + m4 * 4));
    const float* wa = add_w  + ((size_t)e * (LL * MM) + (size_t)l * MM + mq * 16);
    const float* wg = gain_w + ((size_t)e * (LL * MM) + (size_t)l * MM + mq * 16);
    #pragma unroll
    for (int i = 0; i < 4; ++i) {
      wa_n[i] = *(const float4*)(wa + i * 4);
      wg_n[i] = *(const float4*)(wg + i * 4);
    }
  }

  #pragma unroll
  for (int j = 0; j < 7; ++j) {
    float4 mv = mv_n;
    float4 wa_c[4], wg_c[4];
    #pragma unroll
    for (int i = 0; i < 4; ++i) { wa_c[i] = wa_n[i]; wg_c[i] = wg_n[i]; }

    *(float4*)(&lds_mean[j & 1][b16 * 64 + m4 * 4]) = mv;
    __syncthreads();

    if (j < 6) {
      const int si2 = c * 7 + j + 1;
      const int s2 = si2 + (si2 >= tt ? 1 : 0);
      const int e2 = s2 * 63 + (tt > s2 ? tt - 1 : tt);
      mv_n = *(const float4*)(out3 + ((size_t)b16 * 262144 + (size_t)(s2 * 64 + tt) * 64 + m4 * 4));
      const float* wa2 = add_w  + ((size_t)e2 * (LL * MM) + (size_t)l * MM + mq * 16);
      const float* wg2 = gain_w + ((size_t)e2 * (LL * MM) + (size_t)l * MM + mq * 16);
      #pragma unroll
      for (int i = 0; i < 4; ++i) {
        wa_n[i] = *(const float4*)(wa2 + i * 4);
        wg_n[i] = *(const float4*)(wg2 + i * 4);
      }
    }

    #pragma unroll
    for (int i = 0; i < 4; ++i) {
      float4 a  = wa_c[i];
      float4 gq = wg_c[i];
      #pragma unroll
      for (int b = 0; b < BB; ++b) {
        float4 mvv = *(const float4*)(&lds_mean[j & 1][b * 64 + mq * 16 + i * 4]);
        acca[b] = fmaf(a.x,  mvv.x, fmaf(a.y,  mvv.y, fmaf(a.z,  mvv.z, fmaf(a.w,  mvv.w, acca[b]))));
        accg[b] = fmaf(gq.x, mvv.x, fmaf(gq.y, mvv.y, fmaf(gq.z, mvv.z, fmaf(gq.w, mvv.w, accg[b]))));
      }
    }
  }
  #pragma unroll
  for (int b = 0; b < BB; ++b) {
    acca[b] += __shfl_xor(acca[b], 1);
    acca[b] += __shfl_xor(acca[b], 2);
    accg[b] += __shfl_xor(accg[b], 1);
    accg[b] += __shfl_xor(accg[b], 2);
  }
  float* inc_add  = out;
  float* inc_gain = out + 131072;
  #pragma unroll
  for (int jj = 0; jj < 4; ++jj) {
    int b = mq * 4 + jj;
    size_t o = (size_t)b * (RR * LL) + (size_t)tt * LL + l;
    atomicAdd(inc_add + o, acca[b]);
    atomicAdd(inc_gain + o, accg[b]);
  }
}

extern "C" void kernel_launch(void* const* d_in, const int* in_sizes, int n_in,
                              void* d_out, int out_size, void* d_ws, size_t ws_size,
                              hipStream_t stream) {
  const float* source   = (const float*)d_in[0];
  const float* mean_w   = (const float*)d_in[1];
  const float* mean_b   = (const float*)d_in[2];
  const float* logstd_w = (const float*)d_in[3];
  const float* logstd_b = (const float*)d_in[4];
  const float* add_w    = (const float*)d_in[5];
  const float* gain_w   = (const float*)d_in[6];
  const int*   src_idx  = (const int*)d_in[7];
  const int*   tgt_idx  = (const int*)d_in[8];
  float* out = (float*)d_out;

  k_zero<<<1792, 256, 0, stream>>>(out);
  k_edge<<<EE, 256, 0, stream>>>(source, mean_w, mean_b, logstd_w, logstd_b,
                                 src_idx, tgt_idx, out);
  k_inc<<<1152, 256, 0, stream>>>(add_w, gain_w, out);
}

// Round 4
// 475.993 us; speedup vs baseline: 1.0160x; 1.0160x over previous
//
#include <hip/hip_runtime.h>

#define BB 16
#define RR 64
#define SS 128
#define MM 64
#define LL 128
#define EE 4032

// out layout (fp32, concatenated):
// inc_add [131072] | inc_gain [131072] | mean_s [4194304] | logstd_s | msg_s
#define OUT3_OFF 262144
#define ARR_SZ   4194304

// ---------------------------------------------------------------------------
__global__ __launch_bounds__(256) void k_zero(float* __restrict__ out) {
  int tid = blockIdx.x * 256 + threadIdx.x;
  if (tid < 262144) { out[tid] = 0.0f; return; }
  int idx = tid - 262144;          // < 196608
  int a = idx >> 16;
  int r = idx & 65535;
  int b = r >> 12;
  int d = (r >> 6) & 63;
  int m = r & 63;
  out[OUT3_OFF + (size_t)a * ARR_SZ + (size_t)b * 262144 + d * 4160 + m] = 0.0f;
}

// ---------------------------------------------------------------------------
// k_edge v4: DRAM-contiguous weight bursts.
// Theory: v1-v3 all issue weight loads with footprint "16 rows x 64B at
// stride 512B" (per-thread row access) -> time-scattered 64B granules at
// DRAM, capping delivered BW at ~2.75 TB/s regardless of queue depth.
// v4: weights are thread-private (only src is shared), so each wave
// burst-loads its 16 rows as 16 contiguous-1KB dwordx4 instructions
// (8KB mean + 8KB logstd sequential), transpose-stores into LDS chunk
// layout (bijective, bank-uniform), then runs the v3-identical KSTEP loop
// (reads lds + w*2048 + kk*256 + lane*4 = 1024 consecutive bytes,
// measured conflict-free). FMA order bit-identical to v1/v3.
// LDS: src 8KB (stride 128) + weights 64KB = 72KB -> 2 blocks/CU (matches
// the ~2 blocks/CU the HW was running anyway).
// ---------------------------------------------------------------------------
__global__ __launch_bounds__(256) void k_edge(
    const float* __restrict__ source,
    const float* __restrict__ mean_w,
    const float* __restrict__ mean_b,
    const float* __restrict__ logstd_w,
    const float* __restrict__ logstd_b,
    const int* __restrict__ src_idx,
    const int* __restrict__ tgt_idx,
    float* __restrict__ out)
{
  __shared__ float ldsS[2048];            // src 16 x 128, stride 128
  __shared__ float ldsW[16384];           // [mean|logstd][wave][kk][row][sq]
  const int e = blockIdx.x;
  const int tid = threadIdx.x;
  const int w = tid >> 6, lane = tid & 63;
  const int sidx = src_idx[e];
  const int tidx = tgt_idx[e];
  const int m = tid >> 2;                 // 0..63 (= w*16 + (lane>>2))
  const int sq = tid & 3;

  // stage source[:, sidx, :] (16 x 128 floats = 512 float4)
  #pragma unroll
  for (int f0 = 0; f0 < 2; ++f0) {
    int f = tid + f0 * 256;
    int b = f >> 5, s4 = f & 31;
    float4 v = *(const float4*)(source + ((size_t)b * (RR * SS) + (size_t)sidx * SS + s4 * 4));
    *(float4*)(ldsS + b * 128 + s4 * 4) = v;
  }
  const float bm = mean_b[e * MM + m];    // issued pre-barrier (drained by it)
  const float bl = logstd_b[e * MM + m];
  __syncthreads();

  // --- contiguous weight bursts: wave w owns rows 16w..16w+15 (8KB each arr)
  // instr i covers floats [i*256, i*256+256) of the wave tile: 1KB contiguous.
  const float* gw = mean_w   + (size_t)e * (MM * SS) + (size_t)w * 2048;
  const float* gl = logstd_w + (size_t)e * (MM * SS) + (size_t)w * 2048;
  float4 mw[8], lw[8];
  #pragma unroll
  for (int i = 0; i < 8; ++i) mw[i] = *(const float4*)(gw + i * 256 + lane * 4);
  #pragma unroll
  for (int i = 0; i < 8; ++i) lw[i] = *(const float4*)(gl + i * 256 + lane * 4);
  __builtin_amdgcn_sched_barrier(0);      // keep the 16 loads as one burst
  asm volatile("s_waitcnt vmcnt(0)" ::: "memory");

  // --- transpose to chunk layout: lane holds (row 2i+hs, slice kkL, qtr sqL)
  // dest float offset (within wave tile): kkL*256 + (2i+hs)*16 + sqL*4
  {
    const int kkL = (lane >> 2) & 7, hs = lane >> 5, sqL = lane & 3;
    float* wbase = ldsW + w * 2048 + kkL * 256 + hs * 16 + sqL * 4;
    #pragma unroll
    for (int i = 0; i < 8; ++i) {
      *(float4*)(wbase + i * 32)        = mw[i];
      *(float4*)(wbase + 8192 + i * 32) = lw[i];
    }
  }
  asm volatile("s_waitcnt lgkmcnt(0)" ::: "memory");  // cross-lane LDS RAW
  __builtin_amdgcn_sched_barrier(0);

  float accm[BB], accl[BB];
  #pragma unroll
  for (int b = 0; b < BB; ++b) { accm[b] = 0.0f; accl[b] = 0.0f; }

  // --- v3-identical KSTEP loop: chunk reads are 1024 consecutive bytes/wave
  #pragma unroll
  for (int kk = 0; kk < 8; ++kk) {
    float4 a = *(const float4*)(ldsW + w * 2048 + kk * 256 + lane * 4);
    float4 c = *(const float4*)(ldsW + 8192 + w * 2048 + kk * 256 + lane * 4);
    const int soff = sq * 4 + kk * 16;
    #pragma unroll
    for (int b = 0; b < BB; ++b) {
      float4 sv = *(const float4*)(ldsS + b * 128 + soff);
      accm[b] = fmaf(a.x, sv.x, fmaf(a.y, sv.y, fmaf(a.z, sv.z, fmaf(a.w, sv.w, accm[b]))));
      accl[b] = fmaf(c.x, sv.x, fmaf(c.y, sv.y, fmaf(c.z, sv.z, fmaf(c.w, sv.w, accl[b]))));
    }
  }

  // reduce the 4 s-quarters (adjacent lanes)
  #pragma unroll
  for (int b = 0; b < BB; ++b) {
    accm[b] += __shfl_xor(accm[b], 1);
    accm[b] += __shfl_xor(accm[b], 2);
    accl[b] += __shfl_xor(accl[b], 1);
    accl[b] += __shfl_xor(accl[b], 2);
  }

  __syncthreads();                        // everyone done with ldsS; reuse it
  #pragma unroll
  for (int j = 0; j < 4; ++j) {
    int b = sq * 4 + j;
    ldsS[b * 64 + m]        = accm[b] + bm;   // mean tile   [0,1024)
    ldsS[1024 + b * 64 + m] = accl[b] + bl;   // logstd tile [1024,2048)
  }
  __syncthreads();

  float* out3 = out + OUT3_OFF;
  float* out4 = out3 + ARR_SZ;
  float* out5 = out4 + ARR_SZ;
  const size_t rowbase = (size_t)(sidx * RR + tidx) * MM;
  const int b16 = tid >> 4, m4 = tid & 15;
  float4 vm = *(float4*)(ldsS + b16 * 64 + m4 * 4);
  float4 vl = *(float4*)(ldsS + 1024 + b16 * 64 + m4 * 4);
  size_t o = (size_t)b16 * (RR * RR * MM) + rowbase + m4 * 4;
  *(float4*)(out3 + o) = vm;
  *(float4*)(out4 + o) = vl;
  *(float4*)(out5 + o) = vm;
}

// ---------------------------------------------------------------------------
// k_inc: unchanged this round (isolate the contiguous-burst experiment).
// ---------------------------------------------------------------------------
__global__ __launch_bounds__(256) void k_inc(
    const float* __restrict__ add_w,
    const float* __restrict__ gain_w,
    float* __restrict__ out)
{
  __shared__ float lds_mean[2][BB * 64];
  const int g = blockIdx.x;        // 64*2*9 = 1152
  const int tt = g / 18;
  const int r = g % 18;
  const int lh = r / 9;
  const int c = r % 9;
  const int tid = threadIdx.x;
  const int l_loc = tid >> 2;
  const int mq = tid & 3;
  const int l = lh * 64 + l_loc;
  const int b16 = tid >> 4, m4 = tid & 15;

  const float* out3 = out + OUT3_OFF;

  float acca[BB], accg[BB];
  #pragma unroll
  for (int b = 0; b < BB; ++b) { acca[b] = 0.0f; accg[b] = 0.0f; }

  float4 mv_n;
  float4 wa_n[4], wg_n[4];
  {
    const int si = c * 7;
    const int s = si + (si >= tt ? 1 : 0);
    const int e = s * 63 + (tt > s ? tt - 1 : tt);
    mv_n = *(const float4*)(out3 + ((size_t)b16 * 262144 + (size_t)(s * 64 + tt) * 64 + m4 * 4));
    const float* wa = add_w  + ((size_t)e * (LL * MM) + (size_t)l * MM + mq * 16);
    const float* wg = gain_w + ((size_t)e * (LL * MM) + (size_t)l * MM + mq * 16);
    #pragma unroll
    for (int i = 0; i < 4; ++i) {
      wa_n[i] = *(const float4*)(wa + i * 4);
      wg_n[i] = *(const float4*)(wg + i * 4);
    }
  }

  #pragma unroll
  for (int j = 0; j < 7; ++j) {
    float4 mv = mv_n;
    float4 wa_c[4], wg_c[4];
    #pragma unroll
    for (int i = 0; i < 4; ++i) { wa_c[i] = wa_n[i]; wg_c[i] = wg_n[i]; }

    *(float4*)(&lds_mean[j & 1][b16 * 64 + m4 * 4]) = mv;
    __syncthreads();

    if (j < 6) {
      const int si2 = c * 7 + j + 1;
      const int s2 = si2 + (si2 >= tt ? 1 : 0);
      const int e2 = s2 * 63 + (tt > s2 ? tt - 1 : tt);
      mv_n = *(const float4*)(out3 + ((size_t)b16 * 262144 + (size_t)(s2 * 64 + tt) * 64 + m4 * 4));
      const float* wa2 = add_w  + ((size_t)e2 * (LL * MM) + (size_t)l * MM + mq * 16);
      const float* wg2 = gain_w + ((size_t)e2 * (LL * MM) + (size_t)l * MM + mq * 16);
      #pragma unroll
      for (int i = 0; i < 4; ++i) {
        wa_n[i] = *(const float4*)(wa2 + i * 4);
        wg_n[i] = *(const float4*)(wg2 + i * 4);
      }
    }

    #pragma unroll
    for (int i = 0; i < 4; ++i) {
      float4 a  = wa_c[i];
      float4 gq = wg_c[i];
      #pragma unroll
      for (int b = 0; b < BB; ++b) {
        float4 mvv = *(const float4*)(&lds_mean[j & 1][b * 64 + mq * 16 + i * 4]);
        acca[b] = fmaf(a.x,  mvv.x, fmaf(a.y,  mvv.y, fmaf(a.z,  mvv.z, fmaf(a.w,  mvv.w, acca[b]))));
        accg[b] = fmaf(gq.x, mvv.x, fmaf(gq.y, mvv.y, fmaf(gq.z, mvv.z, fmaf(gq.w, mvv.w, accg[b]))));
      }
    }
  }
  #pragma unroll
  for (int b = 0; b < BB; ++b) {
    acca[b] += __shfl_xor(acca[b], 1);
    acca[b] += __shfl_xor(acca[b], 2);
    accg[b] += __shfl_xor(accg[b], 1);
    accg[b] += __shfl_xor(accg[b], 2);
  }
  float* inc_add  = out;
  float* inc_gain = out + 131072;
  #pragma unroll
  for (int jj = 0; jj < 4; ++jj) {
    int b = mq * 4 + jj;
    size_t o = (size_t)b * (RR * LL) + (size_t)tt * LL + l;
    atomicAdd(inc_add + o, acca[b]);
    atomicAdd(inc_gain + o, accg[b]);
  }
}

extern "C" void kernel_launch(void* const* d_in, const int* in_sizes, int n_in,
                              void* d_out, int out_size, void* d_ws, size_t ws_size,
                              hipStream_t stream) {
  const float* source   = (const float*)d_in[0];
  const float* mean_w   = (const float*)d_in[1];
  const float* mean_b   = (const float*)d_in[2];
  const float* logstd_w = (const float*)d_in[3];
  const float* logstd_b = (const float*)d_in[4];
  const float* add_w    = (const float*)d_in[5];
  const float* gain_w   = (const float*)d_in[6];
  const int*   src_idx  = (const int*)d_in[7];
  const int*   tgt_idx  = (const int*)d_in[8];
  float* out = (float*)d_out;

  k_zero<<<1792, 256, 0, stream>>>(out);
  k_edge<<<EE, 256, 0, stream>>>(source, mean_w, mean_b, logstd_w, logstd_b,
                                 src_idx, tgt_idx, out);
  k_inc<<<1152, 256, 0, stream>>>(add_w, gain_w, out);
}